// Round 6
// baseline (10.964 us; speedup 1.0000x reference)
//
#include <hip/hip_runtime.h>
#include <math.h>

// SinenetLayer: h[s,b,d] = a[d] * sum_t x[s,b,t] * sin( 2*pi*i(d)*f*(k_T[t]-tau) + phi[d] )
//   i(d) = d/4 + 1  (32 harmonics), f = exp(nlf*LOG_F_STD + LOG_F_MEAN)
//
// Identity 1: sin(A+phi) = sinA*cos(phi) + cosA*sin(phi)
//   -> 64 per-(s,b) sums (32 harmonics x {sin,cos}); D=128 is an epilogue.
// Identity 2: angle linear in t (step D = 2*pi*i*f*T_WAV) -> phasor rotation.
// Identity 3 (group-of-8): sum_j x_j sin(th+jD) = P sin(th) + Q cos(th) with
//   P = sum x_j c_j, Q = sum x_j s_j (precomputed twiddles).
// NEW (R6): packed-fp32 phasor algebra. Keep u=(s,c), w=(c,-s):
//   acc += P*u + Q*w ; u' = c8*u + s8*w ; w' = c8*w - s8*u
//   -> all float2 ops (v_pk_fma_f32 capable), ~14 insts / 8 samples.
// NEW (R6): no LDS staging (direct broadcast global reads, L1/L2-warm),
//   single barrier, fused float2 reduce+epilogue in wave 0.
//
// One block per (s,b). Lane l of wave w: harmonic (l&31)+1, t-chunk
// w*2+(l>>5) of length 80 (10 macro-steps of 8).

#define S_DIM 25
#define B_DIM 64
#define T_DIM 640
#define D_DIM 128
#define NCHUNK 8
#define CLEN (T_DIM / NCHUNK)   // 80

__device__ __forceinline__ float2 f2fma(float s, float2 b, float2 c) {
    return make_float2(fmaf(s, b.x, c.x), fmaf(s, b.y, c.y));
}
__device__ __forceinline__ float2 f2scale(float2 a, float s) {
    return make_float2(a.x * s, a.y * s);
}

__global__ __launch_bounds__(256) void sinenet_kernel(
    const float* __restrict__ x,    // (S*B, T)
    const float* __restrict__ nlf,  // (S*B)
    const float* __restrict__ tau,  // (S*B)
    const float* __restrict__ a,    // (D)
    const float* __restrict__ phi,  // (D)
    float* __restrict__ out)        // (S*B, D)
{
    __shared__ float2 red[NCHUNK][32];   // (Ssum, Csum) partials

    const int bid   = blockIdx.x;              // flat (s*B + b)
    const int tid   = threadIdx.x;
    const int lane  = tid & 63;
    const int wid   = tid >> 6;
    const int h     = lane & 31;               // harmonic index 0..31
    const int chunk = wid * 2 + (lane >> 5);   // 0..7
    const int t0    = chunk * CLEN;

    // f = exp(nlf*LOG_F_STD + LOG_F_MEAN) via exp2 (hw v_exp_f32)
    const float f     = exp2f(fmaf(nlf[bid], 0.53854075f, 7.2517643f));
    const float tau_v = tau[bid];
    const float i_f   = (float)(h + 1);
    const float T_WAV = 1.0f / 16000.0f;

    // per-step rotation in revolutions: frac(i*f*T_WAV) (exact mod-1)
    const float dr0 = i_f * (f * T_WAV);
    const float dr  = dr0 - floorf(dr0);
    const float sD  = __builtin_amdgcn_sinf(dr);   // sin(2*pi*dr)
    const float cD  = __builtin_amdgcn_cosf(dr);

    // group twiddles (c_j, s_j), j=1..7, plus macro-step rot (c8,s8)
    const float c1 = cD,                        s1 = sD;
    const float c2 = fmaf(c1, cD, -(s1 * sD)),  s2 = fmaf(s1, cD, c1 * sD);
    const float c3 = fmaf(c2, cD, -(s2 * sD)),  s3 = fmaf(s2, cD, c2 * sD);
    const float c4 = fmaf(c3, cD, -(s3 * sD)),  s4 = fmaf(s3, cD, c3 * sD);
    const float c5 = fmaf(c4, cD, -(s4 * sD)),  s5 = fmaf(s4, cD, c4 * sD);
    const float c6 = fmaf(c5, cD, -(s5 * sD)),  s6 = fmaf(s5, cD, c5 * sD);
    const float c7 = fmaf(c6, cD, -(s6 * sD)),  s7 = fmaf(s6, cD, c6 * sD);
    const float c8 = fmaf(c7, cD, -(s7 * sD)),  s8 = fmaf(s7, cD, c7 * sD);
    const float2 t1 = make_float2(c1, s1), t2 = make_float2(c2, s2);
    const float2 t3 = make_float2(c3, s3), t4 = make_float2(c4, s4);
    const float2 t5 = make_float2(c5, s5), t6 = make_float2(c6, s6);
    const float2 t7 = make_float2(c7, s7);

    // initial phasor at t0: i * frac(f*(k_T[t0]-tau)) (integer harmonic -> exact)
    const float tv0 = (float)t0 * T_WAV - tau_v;
    const float ft0 = f * tv0;
    const float u0  = ft0 - floorf(ft0);
    const float p0  = i_f * u0;
    const float w0  = p0 - floorf(p0);
    float2 u = make_float2(__builtin_amdgcn_sinf(w0), __builtin_amdgcn_cosf(w0)); // (s,c)
    float2 w = make_float2(u.y, -u.x);                                            // (c,-s)

    // 10 macro-steps of 8 samples, x read direct from global (broadcast, L1-hot)
    float2 A = make_float2(0.0f, 0.0f);   // (acc_s, acc_c)
    const float4* __restrict__ xp4 =
        reinterpret_cast<const float4*>(x + (size_t)bid * T_DIM + t0);
    #pragma unroll
    for (int m = 0; m < CLEN / 8; ++m) {
        const float4 xa = xp4[2 * m];
        const float4 xb = xp4[2 * m + 1];

        float2 pq = make_float2(xa.x, 0.0f);   // (P,Q); c_0=1, s_0=0
        pq = f2fma(xa.y, t1, pq);
        pq = f2fma(xa.z, t2, pq);
        pq = f2fma(xa.w, t3, pq);
        pq = f2fma(xb.x, t4, pq);
        pq = f2fma(xb.y, t5, pq);
        pq = f2fma(xb.z, t6, pq);
        pq = f2fma(xb.w, t7, pq);

        A = f2fma(pq.x, u, A);                 // += P*(s,c)
        A = f2fma(pq.y, w, A);                 // += Q*(c,-s)

        const float2 un = f2fma( s8, w, f2scale(u, c8));   // rot by 8D
        const float2 wn = f2fma(-s8, u, f2scale(w, c8));
        u = un; w = wn;
    }

    red[chunk][h] = A;
    __syncthreads();

    // wave 0: reduce 8 chunks, apply phi via angle-addition, store 2 outputs/lane
    if (tid < 64) {
        const int hh = tid >> 1;               // harmonic; lane pair splits 4 d's
        float2 v = red[0][hh];
        #pragma unroll
        for (int cc = 1; cc < NCHUNK; ++cc) {
            v.x += red[cc][hh].x;
            v.y += red[cc][hh].y;
        }
        const float2 ph2 = reinterpret_cast<const float2*>(phi)[tid];
        const float2 a2  = reinterpret_cast<const float2*>(a)[tid];
        float pr0 = ph2.x * 0.15915494309189535f;  pr0 -= floorf(pr0);
        float pr1 = ph2.y * 0.15915494309189535f;  pr1 -= floorf(pr1);
        const float o0 = a2.x * fmaf(__builtin_amdgcn_cosf(pr0), v.x,
                                     __builtin_amdgcn_sinf(pr0) * v.y);
        const float o1 = a2.y * fmaf(__builtin_amdgcn_cosf(pr1), v.x,
                                     __builtin_amdgcn_sinf(pr1) * v.y);
        reinterpret_cast<float2*>(out + (size_t)bid * D_DIM)[tid] =
            make_float2(o0, o1);
    }
}

extern "C" void kernel_launch(void* const* d_in, const int* in_sizes, int n_in,
                              void* d_out, int out_size, void* d_ws, size_t ws_size,
                              hipStream_t stream) {
    const float* x   = (const float*)d_in[0];  // (S,B,1,T)
    const float* nlf = (const float*)d_in[1];  // (S,B,1,1)
    const float* tau = (const float*)d_in[2];  // (S,B,1,1)
    const float* a   = (const float*)d_in[3];  // (D)
    const float* phi = (const float*)d_in[4];  // (D)
    float* out = (float*)d_out;                // (S,B,D)

    const int n_sb = S_DIM * B_DIM;            // 1600 blocks, one per (s,b)
    sinenet_kernel<<<n_sb, 256, 0, stream>>>(x, nlf, tau, a, phi, out);
}